// Round 9
// baseline (102.555 us; speedup 1.0000x reference)
//
#include <hip/hip_runtime.h>
#include <hip/hip_bf16.h>

typedef __bf16 bf16_t;
typedef __bf16 bf16x8 __attribute__((ext_vector_type(8)));
typedef float  f32x4  __attribute__((ext_vector_type(4)));

#define GLDS(gsrc, ldst)                                                              \
  __builtin_amdgcn_global_load_lds(                                                   \
      (const __attribute__((address_space(1))) unsigned int*)(gsrc),                  \
      (__attribute__((address_space(3))) unsigned int*)(ldst), 16, 0, 0)

// ---------------- merged convert (q,v -> bf16) + 5-way weight transpose ----------------
struct TArgs {
  const float* src[5];
  bf16_t* dst[5];
  int C[5], Ct[5], off[5], blk0[6];
  float scale[5];
};
struct CTArgs {
  const float* qa; bf16_t* qd;
  const float* va; bf16_t* vd;
  TArgs ta;
};
__global__ void k_convtrans(CTArgs ca) {
  __shared__ float tile[32][33];
  const int bid = blockIdx.x;
  if (bid < 4096) {
    int i = bid * 256 + threadIdx.x;
    const float* s; bf16_t* d;
    if (i < 524288) { s = ca.qa; d = ca.qd; } else { s = ca.va; d = ca.vd; i -= 524288; }
    const float4* p = reinterpret_cast<const float4*>(s) + 2 * (long)i;
    float4 x = p[0], y = p[1];
    bf16x8 o;
    o[0] = (bf16_t)x.x; o[1] = (bf16_t)x.y; o[2] = (bf16_t)x.z; o[3] = (bf16_t)x.w;
    o[4] = (bf16_t)y.x; o[5] = (bf16_t)y.y; o[6] = (bf16_t)y.z; o[7] = (bf16_t)y.w;
    reinterpret_cast<bf16x8*>(d)[i] = o;
    return;
  }
  const TArgs& ta = ca.ta;
  const int tb = bid - 4096;
  int s = 0;
  while (tb >= ta.blk0[s + 1]) ++s;
  const int bi = tb - ta.blk0[s];
  const int Ct = ta.Ct[s];
  const int c0 = (bi % Ct) * 32, r0 = (bi / Ct) * 32;
  const int C = ta.C[s];
  const float* src = ta.src[s];
  const int lx = threadIdx.x & 31, ly = threadIdx.x >> 5;
  #pragma unroll
  for (int i = 0; i < 32; i += 8)
    tile[ly + i][lx] = src[(long)(r0 + ly + i) * C + (c0 + lx)];
  __syncthreads();
  const float sc = ta.scale[s];
  bf16_t* dst = ta.dst[s];
  const int off = ta.off[s];
  #pragma unroll
  for (int i = 0; i < 32; i += 8)
    dst[(long)(c0 + ly + i) * 1024 + off + (r0 + lx)] = (bf16_t)(tile[lx][ly + i] * sc);
}

// ---------------- packed projection GEMMs, 2-phase double-buffered, coalesced epilogue ----------------
struct ProjItem {
  const bf16_t* A; const bf16_t* B; bf16_t* C; const float* bias;
  float bscale; int ldc; int writeT;
};
struct ProjArgs { ProjItem it[3]; };

__global__ __launch_bounds__(256)
void k_gemm_proj(ProjArgs pa) {
  __shared__ char smem[32768];
  const int bid = blockIdx.x;
  const int z = bid < 128 ? 0 : (bid < 256 ? 1 : 2);
  const int local = bid - (z == 0 ? 0 : (z == 1 ? 128 : 256));
  const ProjItem it = pa.it[z];
  const int t = threadIdx.x, lane = t & 63, wid = t >> 6;
  const int wr = wid >> 1, wc = wid & 1;
  const int m0 = (local & 31) * 128, n0 = (local >> 5) * 128;
  const int lhi = lane >> 4, llo = lane & 15;

  const bf16_t* Ab = it.A + (long)m0 * 1024;
  const bf16_t* Bb = it.B + (long)n0 * 1024;

  const int e0 = t * 8,        r0s = e0 >> 5, c0s = e0 & 31;
  const int e1 = (256 + t) * 8, r1s = e1 >> 5, c1s = e1 & 31;

#define PSTAGE(k0_, bsel)                                                     \
  { bf16_t* bA = (bf16_t*)(smem + (bsel) * 16384);                            \
    bf16_t* bB = (bf16_t*)(smem + (bsel) * 16384 + 8192);                     \
    GLDS(Ab + (long)r0s * 1024 + (k0_) + c0s, bA + wid * 512);                \
    GLDS(Ab + (long)r1s * 1024 + (k0_) + c1s, bA + 2048 + wid * 512);         \
    GLDS(Bb + (long)r0s * 1024 + (k0_) + c0s, bB + wid * 512);                \
    GLDS(Bb + (long)r1s * 1024 + (k0_) + c1s, bB + 2048 + wid * 512); }

  f32x4 acc[4][4] = {};
  PSTAGE(0, 0);
  __syncthreads();
  int cur = 0;
  for (int t32 = 0; t32 < 32; ++t32) {
    bf16_t* sA = (bf16_t*)(smem + cur * 16384);
    bf16_t* sB = (bf16_t*)(smem + cur * 16384 + 8192);
    bf16x8 a[4], b[4];
    #pragma unroll
    for (int mi = 0; mi < 4; ++mi)
      a[mi] = *reinterpret_cast<const bf16x8*>(sA + (wr * 64 + mi * 16 + llo) * 32 + lhi * 8);
    #pragma unroll
    for (int ni = 0; ni < 4; ++ni)
      b[ni] = *reinterpret_cast<const bf16x8*>(sB + (wc * 64 + ni * 16 + llo) * 32 + lhi * 8);
    if (t32 < 31) PSTAGE((t32 + 1) * 32, cur ^ 1);
    #pragma unroll
    for (int mi = 0; mi < 4; ++mi)
      #pragma unroll
      for (int ni = 0; ni < 4; ++ni)
        acc[mi][ni] = __builtin_amdgcn_mfma_f32_16x16x32_bf16(a[mi], b[ni], acc[mi][ni], 0, 0, 0);
    __syncthreads();
    cur ^= 1;
  }
#undef PSTAGE

  #pragma unroll
  for (int mi = 0; mi < 4; ++mi)
    #pragma unroll
    for (int ni = 0; ni < 4; ++ni) {
      const float bv = it.bias[n0 + wc * 64 + ni * 16 + llo] * it.bscale;
      #pragma unroll
      for (int r = 0; r < 4; ++r) acc[mi][ni][r] += bv;
    }

  if (!it.writeT) {
    bf16_t* E = (bf16_t*)smem;           // [64][136]
    #pragma unroll
    for (int p = 0; p < 2; ++p) {
      if (wr == p) {
        #pragma unroll
        for (int mi = 0; mi < 4; ++mi)
          #pragma unroll
          for (int ni = 0; ni < 4; ++ni)
            #pragma unroll
            for (int r = 0; r < 4; ++r)
              E[(mi * 16 + lhi * 4 + r) * 136 + wc * 64 + ni * 16 + llo] = (bf16_t)acc[mi][ni][r];
      }
      __syncthreads();
      #pragma unroll
      for (int round = 0; round < 4; ++round) {
        const int row = (t >> 4) + round * 16;
        const int l16 = t & 15;
        float4 v = *reinterpret_cast<const float4*>((char*)E + row * 272 + l16 * 16);
        *reinterpret_cast<float4*>(it.C + (long)(m0 + p * 64 + row) * it.ldc + n0 + l16 * 8) = v;
      }
      __syncthreads();
    }
  } else {
    bf16_t* E = (bf16_t*)smem;           // [128][72]
    #pragma unroll
    for (int p = 0; p < 2; ++p) {
      if (wr == p) {
        #pragma unroll
        for (int mi = 0; mi < 4; ++mi)
          #pragma unroll
          for (int ni = 0; ni < 4; ++ni)
            #pragma unroll
            for (int r = 0; r < 4; ++r)
              E[(wc * 64 + ni * 16 + llo) * 72 + mi * 16 + lhi * 4 + r] = (bf16_t)acc[mi][ni][r];
      }
      __syncthreads();
      #pragma unroll
      for (int round = 0; round < 4; ++round) {
        const int nr = (t >> 3) + round * 32;
        const int l8 = t & 7;
        float4 v = *reinterpret_cast<const float4*>((char*)E + nr * 144 + l8 * 16);
        *reinterpret_cast<float4*>(it.C + (long)(n0 + nr) * it.ldc + m0 + p * 64 + l8 * 8) = v;
      }
      __syncthreads();
    }
  }
}

// ---------------- out-proj GEMM, 2-phase double-buffered, coalesced fp32 epilogue ----------------
__global__ __launch_bounds__(256)
void k_gemm_out(const bf16_t* __restrict__ A_, const bf16_t* __restrict__ B_,
                float* __restrict__ C_, const float* __restrict__ bias) {
  __shared__ char smem[24576];
  const int t = threadIdx.x, lane = t & 63, wid = t >> 6;
  const int wr = wid >> 1, wc = wid & 1;
  const int m0 = blockIdx.x * 64, n0 = blockIdx.y * 128;
  const int lhi = lane >> 4, llo = lane & 15;

  const bf16_t* Ab = A_ + (long)m0 * 1024;
  const bf16_t* Bb = B_ + (long)n0 * 1024;

  const int e0 = t * 8,        r0s = e0 >> 5, c0s = e0 & 31;
  const int e1 = (256 + t) * 8, r1s = e1 >> 5, c1s = e1 & 31;

#define OSTAGE(k0_, bsel)                                                     \
  { bf16_t* bA = (bf16_t*)(smem + (bsel) * 12288);                            \
    bf16_t* bB = (bf16_t*)(smem + (bsel) * 12288 + 4096);                     \
    GLDS(Ab + (long)r0s * 1024 + (k0_) + c0s, bA + wid * 512);                \
    GLDS(Bb + (long)r0s * 1024 + (k0_) + c0s, bB + wid * 512);                \
    GLDS(Bb + (long)r1s * 1024 + (k0_) + c1s, bB + 2048 + wid * 512); }

  f32x4 acc[2][4] = {};
  OSTAGE(0, 0);
  __syncthreads();
  int cur = 0;
  for (int t32 = 0; t32 < 32; ++t32) {
    bf16_t* sA = (bf16_t*)(smem + cur * 12288);
    bf16_t* sB = (bf16_t*)(smem + cur * 12288 + 4096);
    bf16x8 a[2], b[4];
    #pragma unroll
    for (int mi = 0; mi < 2; ++mi)
      a[mi] = *reinterpret_cast<const bf16x8*>(sA + (wr * 32 + mi * 16 + llo) * 32 + lhi * 8);
    #pragma unroll
    for (int ni = 0; ni < 4; ++ni)
      b[ni] = *reinterpret_cast<const bf16x8*>(sB + (wc * 64 + ni * 16 + llo) * 32 + lhi * 8);
    if (t32 < 31) OSTAGE((t32 + 1) * 32, cur ^ 1);
    #pragma unroll
    for (int mi = 0; mi < 2; ++mi)
      #pragma unroll
      for (int ni = 0; ni < 4; ++ni)
        acc[mi][ni] = __builtin_amdgcn_mfma_f32_16x16x32_bf16(a[mi], b[ni], acc[mi][ni], 0, 0, 0);
    __syncthreads();
    cur ^= 1;
  }
#undef OSTAGE

  #pragma unroll
  for (int mi = 0; mi < 2; ++mi)
    #pragma unroll
    for (int ni = 0; ni < 4; ++ni) {
      const float bv = bias[n0 + wc * 64 + ni * 16 + llo];
      #pragma unroll
      for (int r = 0; r < 4; ++r) acc[mi][ni][r] += bv;
    }

  float* E = (float*)smem;               // [32][132]
  #pragma unroll
  for (int p = 0; p < 2; ++p) {
    if (wr == p) {
      #pragma unroll
      for (int mi = 0; mi < 2; ++mi)
        #pragma unroll
        for (int ni = 0; ni < 4; ++ni)
          #pragma unroll
          for (int r = 0; r < 4; ++r)
            E[(mi * 16 + lhi * 4 + r) * 132 + wc * 64 + ni * 16 + llo] = acc[mi][ni][r];
    }
    __syncthreads();
    #pragma unroll
    for (int round = 0; round < 4; ++round) {
      const int row = (t >> 5) + round * 8;
      const int l32 = t & 31;
      float4 v = *reinterpret_cast<const float4*>((char*)E + row * 528 + l32 * 16);
      *reinterpret_cast<float4*>(C_ + (long)(m0 + p * 32 + row) * 1024 + n0 + l32 * 4) = v;
    }
    __syncthreads();
  }
}

// ---------------- merged attention: interleaved fattn (bid%3==0) + GLDS-staged reuse PV ----------------
__global__ __launch_bounds__(256, 3)
void k_attn_all(const bf16_t* __restrict__ qb, const bf16_t* __restrict__ kb,
                const bf16_t* __restrict__ vbT, const float* __restrict__ pe,
                const float* __restrict__ reuse, bf16_t* __restrict__ om) {
  __shared__ char smem[53248];
  const int bid = blockIdx.x;
  const int r3 = bid % 3;
  const int q3 = bid / 3;
  const int lane = threadIdx.x & 63, w = threadIdx.x >> 6;
  const int lhi = lane >> 4, llo = lane & 15;
  const int t = threadIdx.x;

  if (r3 == 0) {
    // ---- fused new-head attention (unchanged structure) ----
    const int fidx = q3;                 // 0..511
    float* pes = (float*)smem;
    char* KtB = smem + 4096;
    char* VtB = smem + 4096 + 16384;
    char* PtB = smem + 4096 + 32768 + w * 4096;

    const int tt = fidx >> 6;
    const int bh = fidx & 63;
    const int b = bh >> 3, h = bh & 7;
    const int t0w = tt * 64 + w * 16;

    const bf16_t* Ksrc = kb + (long)(b * 512) * 512 + h * 64;
    const bf16_t* Vsrc = vbT + (long)(512 + h * 64) * 4096 + b * 512;
    const int krow = w * 32 + (lane >> 3);
    const int kcol = ((lane & 7) ^ (lane >> 3)) << 3;
    const int vn   = w * 16 + (lane >> 4);
    bf16_t* kdst = (bf16_t*)(KtB + w * 4096);
    bf16_t* vdst = (bf16_t*)(VtB + w * 4096);

#define STAGE_K(it_)                                                                   \
  { _Pragma("unroll")                                                                  \
    for (int g = 0; g < 4; ++g)                                                        \
      GLDS(Ksrc + (long)((it_) * 128 + krow + g * 8) * 512 + kcol, kdst + g * 512); }
#define STAGE_V(it_)                                                                   \
  { _Pragma("unroll")                                                                  \
    for (int g = 0; g < 4; ++g)                                                        \
      GLDS(Vsrc + (long)(vn + g * 4) * 4096 + (it_) * 128 +                            \
               (((lane & 15) ^ (g * 4 + (lane >> 4))) << 3),                           \
           vdst + g * 512); }

    STAGE_K(0);
    STAGE_V(0);

    const bf16_t* Qb = qb + (long)(b * 512 + t0w + llo) * 512 + h * 64;
    bf16x8 qf0 = *reinterpret_cast<const bf16x8*>(Qb + lhi * 8);
    bf16x8 qf1 = *reinterpret_cast<const bf16x8*>(Qb + 32 + lhi * 8);
    for (int i = t; i < 1023; i += 256) pes[i] = pe[h * 1023 + i];

    f32x4 oacc[4] = {};
    float lr[4] = {0.f, 0.f, 0.f, 0.f};

    __syncthreads();

    for (int it = 0; it < 4; ++it) {
      const int s0 = it * 128;

      f32x4 acc[8] = {};
      #pragma unroll
      for (int st = 0; st < 8; ++st) {
        const int rowb = st * 16 + llo;
        const int sw = (rowb & 7) << 4;
        bf16x8 kf0 = *reinterpret_cast<const bf16x8*>(KtB + rowb * 128 + ((lhi * 16) ^ sw));
        bf16x8 kf1 = *reinterpret_cast<const bf16x8*>(KtB + rowb * 128 + ((64 + lhi * 16) ^ sw));
        acc[st] = __builtin_amdgcn_mfma_f32_16x16x32_bf16(qf0, kf0, acc[st], 0, 0, 0);
        acc[st] = __builtin_amdgcn_mfma_f32_16x16x32_bf16(qf1, kf1, acc[st], 0, 0, 0);
      }

      __syncthreads();
      if (it < 3) STAGE_K(it + 1);

      #pragma unroll
      for (int r = 0; r < 4; ++r) {
        const int tl = lhi * 4 + r;
        const int bidx = s0 + llo - (t0w + tl) + 511;
        const int swp = (tl & 15) << 4;
        float lp = 0.f;
        #pragma unroll
        for (int st = 0; st < 8; ++st) {
          const float e = __expf(acc[st][r] + pes[bidx + st * 16]);
          lp += e;
          *reinterpret_cast<bf16_t*>(PtB + tl * 256 + (((st * 16 + llo) * 2) ^ swp)) = (bf16_t)e;
        }
        lr[r] += lp;
      }

      const int swa = llo << 4;
      #pragma unroll
      for (int ks = 0; ks < 4; ++ks) {
        bf16x8 pav = *reinterpret_cast<const bf16x8*>(PtB + llo * 256 + ((ks * 64 + lhi * 16) ^ swa));
        #pragma unroll
        for (int ni = 0; ni < 4; ++ni) {
          const int rowv = ni * 16 + llo;
          bf16x8 vf = *reinterpret_cast<const bf16x8*>(VtB + rowv * 256 + ((ks * 64 + lhi * 16) ^ swa));
          oacc[ni] = __builtin_amdgcn_mfma_f32_16x16x32_bf16(pav, vf, oacc[ni], 0, 0, 0);
        }
      }

      __syncthreads();
      if (it < 3) STAGE_V(it + 1);
    }

    #pragma unroll
    for (int r = 0; r < 4; ++r) {
      lr[r] += __shfl_xor(lr[r], 1);
      lr[r] += __shfl_xor(lr[r], 2);
      lr[r] += __shfl_xor(lr[r], 4);
      lr[r] += __shfl_xor(lr[r], 8);
    }

    bf16_t* Ew = (bf16_t*)PtB;          // [16][72]
    #pragma unroll
    for (int ni = 0; ni < 4; ++ni)
      #pragma unroll
      for (int r = 0; r < 4; ++r)
        Ew[(lhi * 4 + r) * 72 + ni * 16 + llo] = (bf16_t)(oacc[ni][r] * (1.f / lr[r]));
    #pragma unroll
    for (int round = 0; round < 2; ++round) {
      const int lr8 = (lane >> 3) + round * 8;
      const int l8 = lane & 7;
      float4 v = *reinterpret_cast<const float4*>((char*)Ew + lr8 * 144 + l8 * 16);
      *reinterpret_cast<float4*>(om + (long)(b * 512 + t0w + lr8) * 1024 + 512 + h * 64 + l8 * 8) = v;
    }
#undef STAGE_K
#undef STAGE_V
    return;
  }

  // ---- reuse-heads PV v2: GLDS-staged fp32 A (swizzled source), waves split N ----
  const int pidx = q3 * 2 + (r3 - 1);    // 0..1023
  const int bh = pidx & 63;
  const int mt = pidx >> 6;
  const int b = bh >> 3, head = bh & 7;
  const int m0 = mt * 32;
  const int wc = w;                       // wave -> n-col group (16 each)

  const float* Asrc = reuse + (long)b * 2097152 + (long)head * 262144 + (long)m0 * 512;
  const bf16_t* Bp = vbT + (long)(head * 64 + wc * 16) * 4096 + b * 512;

  // staging geometry: LDS linear dst D = c*4096 + w*1024 + lane*16 within a 16 KB buffer.
  // logical row = c*8 + w*2 + (lane>>5); col byte = (lane&31)*16, pre-swizzled at source.
  const int arow = w * 2 + (lane >> 5);            // + c*8
  const int acb  = (lane & 31) * 16;
  const int asrcb = acb ^ ((arow & 7) << 5);       // c-invariant (c*8 ≡ 0 mod 8)
  char* adst = smem + w * 1024 + (lane & 31) * 0;  // wave-uniform base (+lane*16 implicit)

#define STAGE_A(ss_, bsel)                                                             \
  { _Pragma("unroll")                                                                  \
    for (int c = 0; c < 4; ++c)                                                        \
      GLDS((const char*)(Asrc + (long)(c * 8 + arow) * 512 + (ss_) * 128) + asrcb,     \
           smem + (bsel) * 16384 + c * 4096 + w * 1024); }

  f32x4 acc[2] = {};
  STAGE_A(0, 0);
  __syncthreads();
  int cur = 0;
  for (int ss = 0; ss < 4; ++ss) {
    if (ss < 3) STAGE_A(ss + 1, cur ^ 1);
    const char* As = smem + cur * 16384;
    #pragma unroll
    for (int ks = 0; ks < 4; ++ks) {
      bf16x8 bfrag = *reinterpret_cast<const bf16x8*>(Bp + (long)llo * 4096 + ss * 128 + ks * 32 + lhi * 8);
      #pragma unroll
      for (int mi = 0; mi < 2; ++mi) {
        const int row = mi * 16 + llo;
        const char* ap = As + row * 512 + ((ks * 128 + lhi * 32) ^ ((row & 7) << 5));
        float4 x = *reinterpret_cast<const float4*>(ap);
        float4 y = *reinterpret_cast<const float4*>(ap + 16);
        bf16x8 av;
        av[0] = (bf16_t)x.x; av[1] = (bf16_t)x.y; av[2] = (bf16_t)x.z; av[3] = (bf16_t)x.w;
        av[4] = (bf16_t)y.x; av[5] = (bf16_t)y.y; av[6] = (bf16_t)y.z; av[7] = (bf16_t)y.w;
        acc[mi] = __builtin_amdgcn_mfma_f32_16x16x32_bf16(av, bfrag, acc[mi], 0, 0, 0);
      }
    }
    __syncthreads();
    cur ^= 1;
  }
#undef STAGE_A

  // coalesced epilogue: stage [32][72] bf16, store 64-col rows as dwordx4
  bf16_t* E = (bf16_t*)smem;
  #pragma unroll
  for (int mi = 0; mi < 2; ++mi)
    #pragma unroll
    for (int r = 0; r < 4; ++r)
      E[(mi * 16 + lhi * 4 + r) * 72 + wc * 16 + llo] = (bf16_t)acc[mi][r];
  __syncthreads();
  {
    const int row = t >> 3, l8 = t & 7;
    float4 v = *reinterpret_cast<const float4*>((char*)E + row * 144 + l8 * 16);
    *reinterpret_cast<float4*>(om + (long)b * 524288 + (long)(m0 + row) * 1024 + head * 64 + l8 * 8) = v;
  }
}

extern "C" void kernel_launch(void* const* d_in, const int* in_sizes, int n_in,
                              void* d_out, int out_size, void* d_ws, size_t ws_size,
                              hipStream_t stream) {
  const float* query = (const float*)d_in[0];
  const float* value = (const float*)d_in[1];
  const float* reuse = (const float*)d_in[2];
  const float* Wq    = (const float*)d_in[3];
  const float* bq    = (const float*)d_in[4];
  const float* Wk    = (const float*)d_in[5];
  const float* bk    = (const float*)d_in[6];
  const float* Wv    = (const float*)d_in[7];
  const float* bv    = (const float*)d_in[8];
  const float* pe    = (const float*)d_in[9];
  const float* WoR   = (const float*)d_in[10];
  const float* WoN   = (const float*)d_in[11];
  const float* bo    = (const float*)d_in[12];
  float* out = (float*)d_out;
  (void)in_sizes; (void)n_in; (void)out_size; (void)ws_size;

  char* w = (char*)d_ws;
  bf16_t* qx  = (bf16_t*)(w);                 // [4096][1024]
  bf16_t* vx  = (bf16_t*)(w + (8L  << 20));   // [4096][1024]
  bf16_t* WqT = (bf16_t*)(w + (16L << 20));   // [512][1024] (pre-scaled by 1/8)
  bf16_t* WkT = (bf16_t*)(w + (17L << 20));   // [512][1024]
  bf16_t* WvT = (bf16_t*)(w + (18L << 20));   // [1024][1024]
  bf16_t* WoT = (bf16_t*)(w + (20L << 20));   // [1024][1024]
  bf16_t* qb  = (bf16_t*)(w + (22L << 20));   // [4096][512]
  bf16_t* kb  = (bf16_t*)(w + (26L << 20));   // [4096][512]
  bf16_t* vbT = (bf16_t*)(w + (30L << 20));   // [1024][4096]
  bf16_t* om  = (bf16_t*)(w + (38L << 20));   // [4096][1024]

  // 1) merged convert + weight transposes
  CTArgs ca;
  ca.qa = query; ca.qd = qx; ca.va = value; ca.vd = vx;
  ca.ta.src[0] = Wq;  ca.ta.dst[0] = WqT; ca.ta.C[0] = 512;  ca.ta.Ct[0] = 16; ca.ta.off[0] = 0;   ca.ta.scale[0] = 0.125f;
  ca.ta.src[1] = Wk;  ca.ta.dst[1] = WkT; ca.ta.C[1] = 512;  ca.ta.Ct[1] = 16; ca.ta.off[1] = 0;   ca.ta.scale[1] = 1.f;
  ca.ta.src[2] = Wv;  ca.ta.dst[2] = WvT; ca.ta.C[2] = 1024; ca.ta.Ct[2] = 32; ca.ta.off[2] = 0;   ca.ta.scale[2] = 1.f;
  ca.ta.src[3] = WoR; ca.ta.dst[3] = WoT; ca.ta.C[3] = 1024; ca.ta.Ct[3] = 32; ca.ta.off[3] = 0;   ca.ta.scale[3] = 1.f;
  ca.ta.src[4] = WoN; ca.ta.dst[4] = WoT; ca.ta.C[4] = 1024; ca.ta.Ct[4] = 32; ca.ta.off[4] = 512; ca.ta.scale[4] = 1.f;
  ca.ta.blk0[0] = 0; ca.ta.blk0[1] = 512; ca.ta.blk0[2] = 1024; ca.ta.blk0[3] = 2048; ca.ta.blk0[4] = 2560; ca.ta.blk0[5] = 3072;
  k_convtrans<<<dim3(7168), 256, 0, stream>>>(ca);

  // 2) packed projections (2-phase pipelined)
  ProjArgs pa;
  pa.it[0] = { qx, WqT, qb,  bq, 0.125f, 512,  0 };
  pa.it[1] = { vx, WkT, kb,  bk, 1.f,    512,  0 };
  pa.it[2] = { vx, WvT, vbT, bv, 1.f,    4096, 1 };
  k_gemm_proj<<<dim3(512), 256, 0, stream>>>(pa);

  // 3) merged attention (interleaved types; GLDS-staged pvr)
  k_attn_all<<<dim3(1536), 256, 0, stream>>>(qb, kb, vbT, pe, reuse, om);

  // 4) out = om @ WoT^T + bo (fp32 out, 2-phase pipelined)
  k_gemm_out<<<dim3(64, 8), 256, 0, stream>>>(om, WoT, out, bo);
}

// Round 10
// 89.047 us; speedup vs baseline: 1.1517x; 1.1517x over previous
//
#include <hip/hip_runtime.h>
#include <hip/hip_bf16.h>

typedef __bf16 bf16_t;
typedef __bf16 bf16x8 __attribute__((ext_vector_type(8)));
typedef float  f32x4  __attribute__((ext_vector_type(4)));

#define GLDS(gsrc, ldst)                                                              \
  __builtin_amdgcn_global_load_lds(                                                   \
      (const __attribute__((address_space(1))) unsigned int*)(gsrc),                  \
      (__attribute__((address_space(3))) unsigned int*)(ldst), 16, 0, 0)

// ---------------- merged convert (q,v -> bf16) + 5-way weight transpose ----------------
struct TArgs {
  const float* src[5];
  bf16_t* dst[5];
  int C[5], Ct[5], off[5], blk0[6];
  float scale[5];
};
struct CTArgs {
  const float* qa; bf16_t* qd;
  const float* va; bf16_t* vd;
  TArgs ta;
};
__global__ void k_convtrans(CTArgs ca) {
  __shared__ float tile[32][33];
  const int bid = blockIdx.x;
  if (bid < 4096) {
    int i = bid * 256 + threadIdx.x;
    const float* s; bf16_t* d;
    if (i < 524288) { s = ca.qa; d = ca.qd; } else { s = ca.va; d = ca.vd; i -= 524288; }
    const float4* p = reinterpret_cast<const float4*>(s) + 2 * (long)i;
    float4 x = p[0], y = p[1];
    bf16x8 o;
    o[0] = (bf16_t)x.x; o[1] = (bf16_t)x.y; o[2] = (bf16_t)x.z; o[3] = (bf16_t)x.w;
    o[4] = (bf16_t)y.x; o[5] = (bf16_t)y.y; o[6] = (bf16_t)y.z; o[7] = (bf16_t)y.w;
    reinterpret_cast<bf16x8*>(d)[i] = o;
    return;
  }
  const TArgs& ta = ca.ta;
  const int tb = bid - 4096;
  int s = 0;
  while (tb >= ta.blk0[s + 1]) ++s;
  const int bi = tb - ta.blk0[s];
  const int Ct = ta.Ct[s];
  const int c0 = (bi % Ct) * 32, r0 = (bi / Ct) * 32;
  const int C = ta.C[s];
  const float* src = ta.src[s];
  const int lx = threadIdx.x & 31, ly = threadIdx.x >> 5;
  #pragma unroll
  for (int i = 0; i < 32; i += 8)
    tile[ly + i][lx] = src[(long)(r0 + ly + i) * C + (c0 + lx)];
  __syncthreads();
  const float sc = ta.scale[s];
  bf16_t* dst = ta.dst[s];
  const int off = ta.off[s];
  #pragma unroll
  for (int i = 0; i < 32; i += 8)
    dst[(long)(c0 + ly + i) * 1024 + off + (r0 + lx)] = (bf16_t)(tile[lx][ly + i] * sc);
}

// ---------------- packed projection GEMMs, 2-phase double-buffered, coalesced epilogue ----------------
struct ProjItem {
  const bf16_t* A; const bf16_t* B; bf16_t* C; const float* bias;
  float bscale; int ldc; int writeT;
};
struct ProjArgs { ProjItem it[3]; };

__global__ __launch_bounds__(256)
void k_gemm_proj(ProjArgs pa) {
  __shared__ char smem[32768];
  const int bid = blockIdx.x;
  const int z = bid < 128 ? 0 : (bid < 256 ? 1 : 2);
  const int local = bid - (z == 0 ? 0 : (z == 1 ? 128 : 256));
  const ProjItem it = pa.it[z];
  const int t = threadIdx.x, lane = t & 63, wid = t >> 6;
  const int wr = wid >> 1, wc = wid & 1;
  const int m0 = (local & 31) * 128, n0 = (local >> 5) * 128;
  const int lhi = lane >> 4, llo = lane & 15;

  const bf16_t* Ab = it.A + (long)m0 * 1024;
  const bf16_t* Bb = it.B + (long)n0 * 1024;

  const int e0 = t * 8,        r0s = e0 >> 5, c0s = e0 & 31;
  const int e1 = (256 + t) * 8, r1s = e1 >> 5, c1s = e1 & 31;

#define PSTAGE(k0_, bsel)                                                     \
  { bf16_t* bA = (bf16_t*)(smem + (bsel) * 16384);                            \
    bf16_t* bB = (bf16_t*)(smem + (bsel) * 16384 + 8192);                     \
    GLDS(Ab + (long)r0s * 1024 + (k0_) + c0s, bA + wid * 512);                \
    GLDS(Ab + (long)r1s * 1024 + (k0_) + c1s, bA + 2048 + wid * 512);         \
    GLDS(Bb + (long)r0s * 1024 + (k0_) + c0s, bB + wid * 512);                \
    GLDS(Bb + (long)r1s * 1024 + (k0_) + c1s, bB + 2048 + wid * 512); }

  f32x4 acc[4][4] = {};
  PSTAGE(0, 0);
  __syncthreads();
  int cur = 0;
  for (int t32 = 0; t32 < 32; ++t32) {
    bf16_t* sA = (bf16_t*)(smem + cur * 16384);
    bf16_t* sB = (bf16_t*)(smem + cur * 16384 + 8192);
    bf16x8 a[4], b[4];
    #pragma unroll
    for (int mi = 0; mi < 4; ++mi)
      a[mi] = *reinterpret_cast<const bf16x8*>(sA + (wr * 64 + mi * 16 + llo) * 32 + lhi * 8);
    #pragma unroll
    for (int ni = 0; ni < 4; ++ni)
      b[ni] = *reinterpret_cast<const bf16x8*>(sB + (wc * 64 + ni * 16 + llo) * 32 + lhi * 8);
    if (t32 < 31) PSTAGE((t32 + 1) * 32, cur ^ 1);
    #pragma unroll
    for (int mi = 0; mi < 4; ++mi)
      #pragma unroll
      for (int ni = 0; ni < 4; ++ni)
        acc[mi][ni] = __builtin_amdgcn_mfma_f32_16x16x32_bf16(a[mi], b[ni], acc[mi][ni], 0, 0, 0);
    __syncthreads();
    cur ^= 1;
  }
#undef PSTAGE

  #pragma unroll
  for (int mi = 0; mi < 4; ++mi)
    #pragma unroll
    for (int ni = 0; ni < 4; ++ni) {
      const float bv = it.bias[n0 + wc * 64 + ni * 16 + llo] * it.bscale;
      #pragma unroll
      for (int r = 0; r < 4; ++r) acc[mi][ni][r] += bv;
    }

  if (!it.writeT) {
    bf16_t* E = (bf16_t*)smem;           // [64][136]
    #pragma unroll
    for (int p = 0; p < 2; ++p) {
      if (wr == p) {
        #pragma unroll
        for (int mi = 0; mi < 4; ++mi)
          #pragma unroll
          for (int ni = 0; ni < 4; ++ni)
            #pragma unroll
            for (int r = 0; r < 4; ++r)
              E[(mi * 16 + lhi * 4 + r) * 136 + wc * 64 + ni * 16 + llo] = (bf16_t)acc[mi][ni][r];
      }
      __syncthreads();
      #pragma unroll
      for (int round = 0; round < 4; ++round) {
        const int row = (t >> 4) + round * 16;
        const int l16 = t & 15;
        float4 v = *reinterpret_cast<const float4*>((char*)E + row * 272 + l16 * 16);
        *reinterpret_cast<float4*>(it.C + (long)(m0 + p * 64 + row) * it.ldc + n0 + l16 * 8) = v;
      }
      __syncthreads();
    }
  } else {
    bf16_t* E = (bf16_t*)smem;           // [128][72]
    #pragma unroll
    for (int p = 0; p < 2; ++p) {
      if (wr == p) {
        #pragma unroll
        for (int mi = 0; mi < 4; ++mi)
          #pragma unroll
          for (int ni = 0; ni < 4; ++ni)
            #pragma unroll
            for (int r = 0; r < 4; ++r)
              E[(wc * 64 + ni * 16 + llo) * 72 + mi * 16 + lhi * 4 + r] = (bf16_t)acc[mi][ni][r];
      }
      __syncthreads();
      #pragma unroll
      for (int round = 0; round < 4; ++round) {
        const int nr = (t >> 3) + round * 32;
        const int l8 = t & 7;
        float4 v = *reinterpret_cast<const float4*>((char*)E + nr * 144 + l8 * 16);
        *reinterpret_cast<float4*>(it.C + (long)(n0 + nr) * it.ldc + m0 + p * 64 + l8 * 8) = v;
      }
      __syncthreads();
    }
  }
}

// ---------------- out-proj GEMM, 2-phase double-buffered, coalesced fp32 epilogue ----------------
__global__ __launch_bounds__(256)
void k_gemm_out(const bf16_t* __restrict__ A_, const bf16_t* __restrict__ B_,
                float* __restrict__ C_, const float* __restrict__ bias) {
  __shared__ char smem[24576];
  const int t = threadIdx.x, lane = t & 63, wid = t >> 6;
  const int wr = wid >> 1, wc = wid & 1;
  const int m0 = blockIdx.x * 64, n0 = blockIdx.y * 128;
  const int lhi = lane >> 4, llo = lane & 15;

  const bf16_t* Ab = A_ + (long)m0 * 1024;
  const bf16_t* Bb = B_ + (long)n0 * 1024;

  const int e0 = t * 8,        r0s = e0 >> 5, c0s = e0 & 31;
  const int e1 = (256 + t) * 8, r1s = e1 >> 5, c1s = e1 & 31;

#define OSTAGE(k0_, bsel)                                                     \
  { bf16_t* bA = (bf16_t*)(smem + (bsel) * 12288);                            \
    bf16_t* bB = (bf16_t*)(smem + (bsel) * 12288 + 4096);                     \
    GLDS(Ab + (long)r0s * 1024 + (k0_) + c0s, bA + wid * 512);                \
    GLDS(Bb + (long)r0s * 1024 + (k0_) + c0s, bB + wid * 512);                \
    GLDS(Bb + (long)r1s * 1024 + (k0_) + c1s, bB + 2048 + wid * 512); }

  f32x4 acc[2][4] = {};
  OSTAGE(0, 0);
  __syncthreads();
  int cur = 0;
  for (int t32 = 0; t32 < 32; ++t32) {
    bf16_t* sA = (bf16_t*)(smem + cur * 12288);
    bf16_t* sB = (bf16_t*)(smem + cur * 12288 + 4096);
    bf16x8 a[2], b[4];
    #pragma unroll
    for (int mi = 0; mi < 2; ++mi)
      a[mi] = *reinterpret_cast<const bf16x8*>(sA + (wr * 32 + mi * 16 + llo) * 32 + lhi * 8);
    #pragma unroll
    for (int ni = 0; ni < 4; ++ni)
      b[ni] = *reinterpret_cast<const bf16x8*>(sB + (wc * 64 + ni * 16 + llo) * 32 + lhi * 8);
    if (t32 < 31) OSTAGE((t32 + 1) * 32, cur ^ 1);
    #pragma unroll
    for (int mi = 0; mi < 2; ++mi)
      #pragma unroll
      for (int ni = 0; ni < 4; ++ni)
        acc[mi][ni] = __builtin_amdgcn_mfma_f32_16x16x32_bf16(a[mi], b[ni], acc[mi][ni], 0, 0, 0);
    __syncthreads();
    cur ^= 1;
  }
#undef OSTAGE

  #pragma unroll
  for (int mi = 0; mi < 2; ++mi)
    #pragma unroll
    for (int ni = 0; ni < 4; ++ni) {
      const float bv = bias[n0 + wc * 64 + ni * 16 + llo];
      #pragma unroll
      for (int r = 0; r < 4; ++r) acc[mi][ni][r] += bv;
    }

  float* E = (float*)smem;               // [32][132]
  #pragma unroll
  for (int p = 0; p < 2; ++p) {
    if (wr == p) {
      #pragma unroll
      for (int mi = 0; mi < 2; ++mi)
        #pragma unroll
        for (int ni = 0; ni < 4; ++ni)
          #pragma unroll
          for (int r = 0; r < 4; ++r)
            E[(mi * 16 + lhi * 4 + r) * 132 + wc * 64 + ni * 16 + llo] = acc[mi][ni][r];
    }
    __syncthreads();
    #pragma unroll
    for (int round = 0; round < 4; ++round) {
      const int row = (t >> 5) + round * 8;
      const int l32 = t & 31;
      float4 v = *reinterpret_cast<const float4*>((char*)E + row * 528 + l32 * 16);
      *reinterpret_cast<float4*>(C_ + (long)(m0 + p * 32 + row) * 1024 + n0 + l32 * 4) = v;
    }
    __syncthreads();
  }
}

// ---------------- merged attention: interleaved fattn (SBLK=64, 28KB LDS) + r8 register pvr ----------------
__global__ __launch_bounds__(256, 5)
void k_attn_all(const bf16_t* __restrict__ qb, const bf16_t* __restrict__ kb,
                const bf16_t* __restrict__ vbT, const float* __restrict__ pe,
                const float* __restrict__ reuse, bf16_t* __restrict__ om) {
  __shared__ char smem[28672];
  const int bid = blockIdx.x;
  const int r3 = bid % 3;
  const int q3 = bid / 3;
  const int lane = threadIdx.x & 63, w = threadIdx.x >> 6;
  const int lhi = lane >> 4, llo = lane & 15;

  if (r3 == 0) {
    // ---- fused new-head attention, s-tile 64 ----
    float* pes = (float*)smem;                    // 4 KB
    char* KtB = smem + 4096;                      // [64 s][128 B] swz  8 KB
    char* VtB = smem + 12288;                     // [64 n][128 B] swz  8 KB
    char* PtB = smem + 20480 + w * 2048;          // per-wave [16 t][128 B] swz

    const int fidx = q3;                          // 0..511
    const int tt = fidx >> 6;
    const int bh = fidx & 63;
    const int b = bh >> 3, h = bh & 7;
    const int t0w = tt * 64 + w * 16;

    const bf16_t* Ksrc = kb + (long)(b * 512) * 512 + h * 64;
    const bf16_t* Vsrc = vbT + (long)(512 + h * 64) * 4096 + b * 512;
    const int krow = w * 16 + (lane >> 3);        // + g*8 (g=0,1); also V's n-row
    const int kcol = ((lane & 7) ^ (lane >> 3)) << 3;   // swizzled 8-elem slot
    bf16_t* kdst = (bf16_t*)(KtB + w * 2048);
    bf16_t* vdst = (bf16_t*)(VtB + w * 2048);

#define STAGE_K(it_)                                                                   \
  { _Pragma("unroll")                                                                  \
    for (int g = 0; g < 2; ++g)                                                        \
      GLDS(Ksrc + (long)((it_) * 64 + krow + g * 8) * 512 + kcol, kdst + g * 512); }
#define STAGE_V(it_)                                                                   \
  { _Pragma("unroll")                                                                  \
    for (int g = 0; g < 2; ++g)                                                        \
      GLDS(Vsrc + (long)(krow + g * 8) * 4096 + (it_) * 64 + kcol, vdst + g * 512); }

    STAGE_K(0);
    STAGE_V(0);

    const bf16_t* Qb = qb + (long)(b * 512 + t0w + llo) * 512 + h * 64;
    bf16x8 qf0 = *reinterpret_cast<const bf16x8*>(Qb + lhi * 8);
    bf16x8 qf1 = *reinterpret_cast<const bf16x8*>(Qb + 32 + lhi * 8);
    for (int i = threadIdx.x; i < 1023; i += 256) pes[i] = pe[h * 1023 + i];

    f32x4 oacc[4] = {};
    float lr[4] = {0.f, 0.f, 0.f, 0.f};

    __syncthreads();  // tile 0 staged (barrier drains vmcnt)

    for (int it = 0; it < 8; ++it) {
      const int s0 = it * 64;

      // QK^T: acc[st] -> s = s0 + st*16 + llo, t = t0w + lhi*4 + r
      f32x4 acc[4] = {};
      #pragma unroll
      for (int st = 0; st < 4; ++st) {
        const int rowb = st * 16 + llo;
        const int sw = (rowb & 7) << 4;
        bf16x8 kf0 = *reinterpret_cast<const bf16x8*>(KtB + rowb * 128 + ((lhi * 16) ^ sw));
        bf16x8 kf1 = *reinterpret_cast<const bf16x8*>(KtB + rowb * 128 + ((64 + lhi * 16) ^ sw));
        acc[st] = __builtin_amdgcn_mfma_f32_16x16x32_bf16(qf0, kf0, acc[st], 0, 0, 0);
        acc[st] = __builtin_amdgcn_mfma_f32_16x16x32_bf16(qf1, kf1, acc[st], 0, 0, 0);
      }

      __syncthreads();                 // all waves done reading Kt; drains STAGE_V(it)
      if (it < 7) STAGE_K(it + 1);     // hides under softmax + PV

      // bias + exp (no max-subtract; logits bounded) + P -> LDS + denominator
      #pragma unroll
      for (int r = 0; r < 4; ++r) {
        const int tl = lhi * 4 + r;
        const int bidx = s0 + llo - (t0w + tl) + 511;
        const int swp = (tl & 7) << 4;
        float lp = 0.f;
        #pragma unroll
        for (int st = 0; st < 4; ++st) {
          const float e = __expf(acc[st][r] + pes[bidx + st * 16]);
          lp += e;
          *reinterpret_cast<bf16_t*>(PtB + tl * 128 + (((st * 16 + llo) * 2) ^ swp)) = (bf16_t)e;
        }
        lr[r] += lp;
      }

      // PV accumulate: A = P rows (t = llo), B = V rows (n), k = s-tile
      const int swa = (llo & 7) << 4;
      #pragma unroll
      for (int ks = 0; ks < 2; ++ks) {
        bf16x8 pav = *reinterpret_cast<const bf16x8*>(PtB + llo * 128 + ((ks * 64 + lhi * 16) ^ swa));
        #pragma unroll
        for (int ni = 0; ni < 4; ++ni) {
          const int rowv = ni * 16 + llo;
          bf16x8 vf = *reinterpret_cast<const bf16x8*>(VtB + rowv * 128 + ((ks * 64 + lhi * 16) ^ ((rowv & 7) << 4)));
          oacc[ni] = __builtin_amdgcn_mfma_f32_16x16x32_bf16(pav, vf, oacc[ni], 0, 0, 0);
        }
      }

      __syncthreads();                 // all waves done reading Vt; drains STAGE_K(it+1)
      if (it < 7) STAGE_V(it + 1);     // hides under next QK
    }

    #pragma unroll
    for (int r = 0; r < 4; ++r) {
      lr[r] += __shfl_xor(lr[r], 1);
      lr[r] += __shfl_xor(lr[r], 2);
      lr[r] += __shfl_xor(lr[r], 4);
      lr[r] += __shfl_xor(lr[r], 8);
    }

    // per-wave [16][72] staging in (now-free) Kt/Vt region, coalesced 128 B stores
    bf16_t* Ew = (bf16_t*)(smem + 4096 + w * 4096);
    #pragma unroll
    for (int ni = 0; ni < 4; ++ni)
      #pragma unroll
      for (int r = 0; r < 4; ++r)
        Ew[(lhi * 4 + r) * 72 + ni * 16 + llo] = (bf16_t)(oacc[ni][r] * (1.f / lr[r]));
    #pragma unroll
    for (int round = 0; round < 2; ++round) {
      const int lr8 = (lane >> 3) + round * 8;
      const int l8 = lane & 7;
      float4 v = *reinterpret_cast<const float4*>((char*)Ew + lr8 * 144 + l8 * 16);
      *reinterpret_cast<float4*>(om + (long)(b * 512 + t0w + lr8) * 1024 + 512 + h * 64 + l8 * 8) = v;
    }
#undef STAGE_K
#undef STAGE_V
    return;
  }

  // ---- reuse-heads PV (r8 register double-buffer, split-K=4) ----
  typedef float RedRow[32][68];
  RedRow* red = (RedRow*)smem;           // 17.4 KB
  const int pidx = q3 * 2 + (r3 - 1);    // 0..1023
  const int bh = pidx & 63;
  const int mt = pidx >> 6;
  const int b = bh >> 3, head = bh & 7;
  const int m0 = mt * 32;
  const int ks0 = w * 128;

  const float*  Af = reuse + (long)b * 2097152 + (long)head * 262144;
  const bf16_t* Bp = vbT + (long)(head * 64) * 4096 + b * 512;

  f32x4 acc[2][4] = {};
  float4 Ax[2][2][2];
  bf16x8 Bx[2][4];

  #define PV_LOAD(kq, buf)                                                              \
    {                                                                                   \
      const int kk = ks0 + (kq) * 32 + lhi * 8;                                         \
      _Pragma("unroll")                                                                 \
      for (int mi = 0; mi < 2; ++mi) {                                                  \
        const float4* p = reinterpret_cast<const float4*>(Af + (long)(m0 + mi * 16 + llo) * 512 + kk); \
        Ax[buf][mi][0] = p[0];                                                          \
        Ax[buf][mi][1] = p[1];                                                          \
      }                                                                                 \
      _Pragma("unroll")                                                                 \
      for (int ni = 0; ni < 4; ++ni)                                                    \
        Bx[buf][ni] = *reinterpret_cast<const bf16x8*>(Bp + (long)(ni * 16 + llo) * 4096 + kk); \
    }

  PV_LOAD(0, 0);
  #pragma unroll
  for (int kq = 0; kq < 4; ++kq) {
    const int cb = kq & 1;
    if (kq < 3) {
      const int nb = (kq + 1) & 1;
      PV_LOAD(kq + 1, nb);
    }
    bf16x8 a[2];
    #pragma unroll
    for (int mi = 0; mi < 2; ++mi) {
      float4 x = Ax[cb][mi][0], y = Ax[cb][mi][1];
      bf16x8 tv;
      tv[0] = (bf16_t)x.x; tv[1] = (bf16_t)x.y; tv[2] = (bf16_t)x.z; tv[3] = (bf16_t)x.w;
      tv[4] = (bf16_t)y.x; tv[5] = (bf16_t)y.y; tv[6] = (bf16_t)y.z; tv[7] = (bf16_t)y.w;
      a[mi] = tv;
    }
    #pragma unroll
    for (int mi = 0; mi < 2; ++mi)
      #pragma unroll
      for (int ni = 0; ni < 4; ++ni)
        acc[mi][ni] = __builtin_amdgcn_mfma_f32_16x16x32_bf16(a[mi], Bx[cb][ni], acc[mi][ni], 0, 0, 0);
  }
  #undef PV_LOAD

  if (w >= 2) {
    #pragma unroll
    for (int mi = 0; mi < 2; ++mi)
      #pragma unroll
      for (int ni = 0; ni < 4; ++ni)
        #pragma unroll
        for (int r = 0; r < 4; ++r)
          red[w - 2][mi * 16 + lhi * 4 + r][ni * 16 + llo] = acc[mi][ni][r];
  }
  __syncthreads();
  if (w < 2) {
    #pragma unroll
    for (int mi = 0; mi < 2; ++mi)
      #pragma unroll
      for (int ni = 0; ni < 4; ++ni)
        #pragma unroll
        for (int r = 0; r < 4; ++r)
          acc[mi][ni][r] += red[w][mi * 16 + lhi * 4 + r][ni * 16 + llo];
  }
  __syncthreads();
  if (w == 1) {
    #pragma unroll
    for (int mi = 0; mi < 2; ++mi)
      #pragma unroll
      for (int ni = 0; ni < 4; ++ni)
        #pragma unroll
        for (int r = 0; r < 4; ++r)
          red[0][mi * 16 + lhi * 4 + r][ni * 16 + llo] = acc[mi][ni][r];
  }
  __syncthreads();
  if (w == 0) {
    bf16_t* E = (bf16_t*)&red[1][0][0];
    #pragma unroll
    for (int mi = 0; mi < 2; ++mi)
      #pragma unroll
      for (int ni = 0; ni < 4; ++ni)
        #pragma unroll
        for (int r = 0; r < 4; ++r) {
          const int mr = mi * 16 + lhi * 4 + r;
          const int nn = ni * 16 + llo;
          E[mr * 72 + nn] = (bf16_t)(acc[mi][ni][r] + red[0][mr][nn]);
        }
    bf16_t* Cb = om + (long)b * 524288 + head * 64;
    #pragma unroll
    for (int round = 0; round < 4; ++round) {
      const int row = (lane >> 3) + round * 8;
      const int l8 = lane & 7;
      float4 v = *reinterpret_cast<const float4*>((char*)E + row * 144 + l8 * 16);
      *reinterpret_cast<float4*>(Cb + (long)(m0 + row) * 1024 + l8 * 8) = v;
    }
  }
}

extern "C" void kernel_launch(void* const* d_in, const int* in_sizes, int n_in,
                              void* d_out, int out_size, void* d_ws, size_t ws_size,
                              hipStream_t stream) {
  const float* query = (const float*)d_in[0];
  const float* value = (const float*)d_in[1];
  const float* reuse = (const float*)d_in[2];
  const float* Wq    = (const float*)d_in[3];
  const float* bq    = (const float*)d_in[4];
  const float* Wk    = (const float*)d_in[5];
  const float* bk    = (const float*)d_in[6];
  const float* Wv    = (const float*)d_in[7];
  const float* bv    = (const float*)d_in[8];
  const float* pe    = (const float*)d_in[9];
  const float* WoR   = (const float*)d_in[10];
  const float* WoN   = (const float*)d_in[11];
  const float* bo    = (const float*)d_in[12];
  float* out = (float*)d_out;
  (void)in_sizes; (void)n_in; (void)out_size; (void)ws_size;

  char* w = (char*)d_ws;
  bf16_t* qx  = (bf16_t*)(w);                 // [4096][1024]
  bf16_t* vx  = (bf16_t*)(w + (8L  << 20));   // [4096][1024]
  bf16_t* WqT = (bf16_t*)(w + (16L << 20));   // [512][1024] (pre-scaled by 1/8)
  bf16_t* WkT = (bf16_t*)(w + (17L << 20));   // [512][1024]
  bf16_t* WvT = (bf16_t*)(w + (18L << 20));   // [1024][1024]
  bf16_t* WoT = (bf16_t*)(w + (20L << 20));   // [1024][1024]
  bf16_t* qb  = (bf16_t*)(w + (22L << 20));   // [4096][512]
  bf16_t* kb  = (bf16_t*)(w + (26L << 20));   // [4096][512]
  bf16_t* vbT = (bf16_t*)(w + (30L << 20));   // [1024][4096]
  bf16_t* om  = (bf16_t*)(w + (38L << 20));   // [4096][1024]

  // 1) merged convert + weight transposes
  CTArgs ca;
  ca.qa = query; ca.qd = qx; ca.va = value; ca.vd = vx;
  ca.ta.src[0] = Wq;  ca.ta.dst[0] = WqT; ca.ta.C[0] = 512;  ca.ta.Ct[0] = 16; ca.ta.off[0] = 0;   ca.ta.scale[0] = 0.125f;
  ca.ta.src[1] = Wk;  ca.ta.dst[1] = WkT; ca.ta.C[1] = 512;  ca.ta.Ct[1] = 16; ca.ta.off[1] = 0;   ca.ta.scale[1] = 1.f;
  ca.ta.src[2] = Wv;  ca.ta.dst[2] = WvT; ca.ta.C[2] = 1024; ca.ta.Ct[2] = 32; ca.ta.off[2] = 0;   ca.ta.scale[2] = 1.f;
  ca.ta.src[3] = WoR; ca.ta.dst[3] = WoT; ca.ta.C[3] = 1024; ca.ta.Ct[3] = 32; ca.ta.off[3] = 0;   ca.ta.scale[3] = 1.f;
  ca.ta.src[4] = WoN; ca.ta.dst[4] = WoT; ca.ta.C[4] = 1024; ca.ta.Ct[4] = 32; ca.ta.off[4] = 512; ca.ta.scale[4] = 1.f;
  ca.ta.blk0[0] = 0; ca.ta.blk0[1] = 512; ca.ta.blk0[2] = 1024; ca.ta.blk0[3] = 2048; ca.ta.blk0[4] = 2560; ca.ta.blk0[5] = 3072;
  k_convtrans<<<dim3(7168), 256, 0, stream>>>(ca);

  // 2) packed projections (2-phase pipelined)
  ProjArgs pa;
  pa.it[0] = { qx, WqT, qb,  bq, 0.125f, 512,  0 };
  pa.it[1] = { vx, WkT, kb,  bk, 1.f,    512,  0 };
  pa.it[2] = { vx, WvT, vbT, bv, 1.f,    4096, 1 };
  k_gemm_proj<<<dim3(512), 256, 0, stream>>>(pa);

  // 3) merged attention (interleaved types; 28 KB LDS -> 5 blocks/CU)
  k_attn_all<<<dim3(1536), 256, 0, stream>>>(qb, kb, vbT, pe, reuse, om);

  // 4) out = om @ WoT^T + bo (fp32 out, 2-phase pipelined)
  k_gemm_out<<<dim3(64, 8), 256, 0, stream>>>(om, WoT, out, bo);
}